// Round 1
// 77.845 us; speedup vs baseline: 1.0020x; 1.0020x over previous
//
#include <hip/hip_runtime.h>

// QuantumLLPModel: probs[b,s] for s in [0,10) over 16 qubits.
// Identity: classes 0..9 differ only in qubits 12..15; the shared product
// over qubits 0..11 and the 1/2 factors of cos^2(a/2)=(1+cos a)/2 cancel
// under normalization. Per sample: 4 cos + ~25 FMAs.
//
// cos(pi*x + p) = cos(2*pi*(0.5*x + p/(2*pi))) -> feed v_cos_f32 directly
// with pre-scaled revolutions (|revs| < ~1.3, well inside HW domain).
static constexpr float INV2PI = 0.15915494309189535f;

__global__ __launch_bounds__(256) void qllp_kernel(
    const float* __restrict__ x, const float* __restrict__ params,
    float* __restrict__ out, int batch)
{
    __shared__ float sm[2560];  // 256 samples x 10 classes, sample-major
    const int tid = threadIdx.x;
    const long long b = (long long)blockIdx.x * 256 + tid;

    // uniform scalar loads, qubits 12..15 only, pre-scaled to revolutions
    const float r12 = params[12] * INV2PI;
    const float r13 = params[13] * INV2PI;
    const float r14 = params[14] * INV2PI;
    const float r15 = params[15] * INV2PI;

    if (b < batch) {
        // row tail: elements 12..15 of the 16-float row, 16B-aligned
        const float4 xv = reinterpret_cast<const float4*>(x)[b * 4 + 3];
        const float c12 = __builtin_amdgcn_cosf(fmaf(0.5f, xv.x, r12));
        const float c13 = __builtin_amdgcn_cosf(fmaf(0.5f, xv.y, r13));
        const float c14 = __builtin_amdgcn_cosf(fmaf(0.5f, xv.z, r14));
        const float c15 = __builtin_amdgcn_cosf(fmaf(0.5f, xv.w, r15));
        // unnormalized per-qubit probs (1/2 factors cancel in normalization)
        const float a0 = 1.f + c12, a1 = 1.f - c12;   // qubit 12 (bit 3)
        const float b0 = 1.f + c13, b1 = 1.f - c13;   // qubit 13 (bit 2)
        const float d0 = 1.f + c14, d1 = 1.f - c14;   // qubit 14 (bit 1)
        const float e0 = 1.f + c15, e1 = 1.f - c15;   // qubit 15 (bit 0)
        const float m0 = d0 * e0, m1 = d0 * e1, m2 = d1 * e0, m3 = d1 * e1;
        const float n0 = a0 * b0, n1 = a0 * b1, n2 = a1 * b0;
        const float t0 = n0 * m0, t1 = n0 * m1, t2 = n0 * m2, t3 = n0 * m3;
        const float t4 = n1 * m0, t5 = n1 * m1, t6 = n1 * m2, t7 = n1 * m3;
        const float t8 = n2 * m0, t9 = n2 * m1;
        const float sum = ((t0 + t1) + (t2 + t3))
                        + ((t4 + t5) + (t6 + t7))
                        + (t8 + t9);
        const float inv = 1.0f / sum;
        // vectorized LDS writes: base tid*40B is 8B-aligned -> 5x ds_write_b64
        float2* smv = reinterpret_cast<float2*>(&sm[tid * 10]);
        smv[0] = make_float2(t0 * inv, t1 * inv);
        smv[1] = make_float2(t2 * inv, t3 * inv);
        smv[2] = make_float2(t4 * inv, t5 * inv);
        smv[3] = make_float2(t6 * inv, t7 * inv);
        smv[4] = make_float2(t8 * inv, t9 * inv);
    }
    __syncthreads();

    // coalesced drain of the block's 2560 contiguous floats (640 float4)
    const long long base = (long long)blockIdx.x * 2560;
    float* outb = out + base;
    if (base + 2560 <= (long long)batch * 10) {
        // full block: 2.5 float4 stores/thread, per-block base 10240B (16B-aligned)
        const float4* smq = reinterpret_cast<const float4*>(sm);
        float4* oq = reinterpret_cast<float4*>(outb);
        oq[tid]       = smq[tid];
        oq[256 + tid] = smq[256 + tid];
        if (tid < 128) oq[512 + tid] = smq[512 + tid];
    } else {
        // tail block: guarded scalar path
        const long long lim = (long long)batch * 10 - base;
#pragma unroll
        for (int k = 0; k < 10; ++k) {
            const int f = k * 256 + tid;
            if (f < lim) outb[f] = sm[f];
        }
    }
}

extern "C" void kernel_launch(void* const* d_in, const int* in_sizes, int n_in,
                              void* d_out, int out_size, void* d_ws, size_t ws_size,
                              hipStream_t stream) {
    const float* x      = (const float*)d_in[0];
    const float* params = (const float*)d_in[1];
    float* out = (float*)d_out;
    const int batch  = in_sizes[0] / 16;
    const int blocks = (batch + 255) / 256;
    qllp_kernel<<<blocks, 256, 0, stream>>>(x, params, out, batch);
}